// Round 7
// baseline (68.790 us; speedup 1.0000x reference)
//
#include <hip/hip_runtime.h>

// Problem constants (match reference)
#define BB   8
#define CC   1024
#define TT   4096
#define HH   16
#define KK   31
#define PADD 15

#define RPT  16                  // outputs per thread (256 threads * 16 = 4096 = T)
#define NCH  12                  // float4 window chunks per thread (48 floats)

typedef float floatx4 __attribute__((ext_vector_type(4)));

// window element e corresponds to x[a - 16 + e]; out[a+r] uses e = r+1+k
#define XV(e) vv[(e) >> 2][(e) & 3]

// --- softmax over the 31 taps of each of the 16 heads -> d_ws ---
__global__ void lwconv_softmax_w(const float* __restrict__ w, float* __restrict__ wsm) {
    int h = threadIdx.x;
    if (h < HH) {
        float buf[KK];
        float m = -1e30f;
        #pragma unroll
        for (int k = 0; k < KK; ++k) { buf[k] = w[h * KK + k]; m = fmaxf(m, buf[k]); }
        float s = 0.f;
        #pragma unroll
        for (int k = 0; k < KK; ++k) { buf[k] = expf(buf[k] - m); s += buf[k]; }
        float inv = 1.f / s;
        #pragma unroll
        for (int k = 0; k < KK; ++k) wsm[h * KK + k] = buf[k] * inv;
    }
}

// --- main: one block = one row; thread = 16 consecutive t; window in registers ---
// out[t] = bias + sum_k w[k] * x[t + k - 15]
__global__ __launch_bounds__(256, 4) void lwconv_main(const float* __restrict__ inp,
                                                      const float* __restrict__ wsm,
                                                      const float* __restrict__ bias,
                                                      float* __restrict__ out) {
    const int row  = blockIdx.x;         // b*C + ch, 0..8191
    const int ch   = row & (CC - 1);
    const int head = ch >> 6;            // 64 channels per head
    const int tid  = threadIdx.x;
    const int a    = tid << 4;           // first output index of this thread

    const float* rowp = inp + (size_t)row * TT;

    // ---- issue all 12 window loads; only tid 0 / tid 255 have OOB chunks ----
    floatx4 vv[NCH];
    #pragma unroll
    for (int c = 0; c < NCH; ++c) {
        const int ge = a - 16 + 4 * c;   // global element index of chunk start
        if (ge >= 0 && ge <= TT - 4)
            vv[c] = *reinterpret_cast<const floatx4*>(rowp + ge);
        else
            vv[c] = (floatx4)0.f;        // whole chunk is zero padding
    }

    // ---- uniform pre-softmaxed weights + bias (scalar loads; fill load shadow) ----
    const float* wh = wsm + head * KK;
    float w[KK];
    #pragma unroll
    for (int k = 0; k < KK; ++k) w[k] = wh[k];
    const float bval = bias[head];

    // Keep-alive: all 12 chunks must be materialized in registers here ->
    // regalloc cannot roll the loads into batches; single vmcnt wait.
    asm volatile("" :: "v"(vv[0]), "v"(vv[1]), "v"(vv[2]),  "v"(vv[3]),
                       "v"(vv[4]), "v"(vv[5]), "v"(vv[6]),  "v"(vv[7]),
                       "v"(vv[8]), "v"(vv[9]), "v"(vv[10]), "v"(vv[11]));

    float acc[RPT];
    #pragma unroll
    for (int r = 0; r < RPT; ++r) acc[r] = bval;

    #pragma unroll
    for (int k = 0; k < KK; ++k) {
        #pragma unroll
        for (int r = 0; r < RPT; ++r) {
            acc[r] = fmaf(XV(r + 1 + k), w[k], acc[r]);
        }
    }

    float* orow = out + (size_t)row * TT + a;
    #pragma unroll
    for (int c = 0; c < RPT / 4; ++c) {
        floatx4 o = { acc[4 * c], acc[4 * c + 1], acc[4 * c + 2], acc[4 * c + 3] };
        *reinterpret_cast<floatx4*>(orow + 4 * c) = o;
    }
}

extern "C" void kernel_launch(void* const* d_in, const int* in_sizes, int n_in,
                              void* d_out, int out_size, void* d_ws, size_t ws_size,
                              hipStream_t stream) {
    const float* inp    = (const float*)d_in[0];   // (B, C, T) fp32
    const float* weight = (const float*)d_in[1];   // (H, 1, K) fp32
    const float* bias   = (const float*)d_in[2];   // (H,) fp32
    float* out = (float*)d_out;
    float* wsm = (float*)d_ws;                     // H*K softmaxed weights

    lwconv_softmax_w<<<1, 64, 0, stream>>>(weight, wsm);

    const int rows = BB * CC;                      // 8192 = one block per row
    lwconv_main<<<rows, 256, 0, stream>>>(inp, wsm, bias, out);
}